// Round 1
// baseline (353.400 us; speedup 1.0000x reference)
//
#include <hip/hip_runtime.h>
#include <cmath>

// MLDR loss on MI355X.
// Pipeline:
//  K1: raw inputs -> P[16][T] (0.5*(x0±x1)^2 clipped) + per-chunk local EMA
//      end values for all 6 coefs (weighted block reduction, weights a^(255-j)).
//  K2: tiny serial scan over 128 chunk carries per (row,coef) -> global chunk-end EMA Y.
//  per pair k (3x):
//    K3: long-coef EMA reconstruction with carries (intra-block shuffle scan),
//        writes E_k[8][T] = log(yP/yT).
//    K4: short-coef EMA reconstruction + D = log(yP/yT), reads E at (t+shift)%T,
//        accumulates |D-E| -> per-block fp32 partials.
//  K5: fp64 sum of 3072 partials, /(8*T) -> out scalar.

#define T_LEN    1048576
#define CHUNKS   128
#define CHUNK_LEN 8192      // CHUNKS * CHUNK_LEN == T_LEN
#define NTHREADS 256
#define SEG      32         // CHUNK_LEN / NTHREADS
#define NROWS    16         // 8 pred rows + 8 true rows
#define NCOEF    6          // [s0,l0,s1,l1,s2,l2]
#define EPS_CLIP 1e-8f

struct Coefs {
  float c[NCOEF];
  float d[NCOEF];
  float apowK1[NCOEF][8];   // (d^SEG)^(2^i), i=0..7
  float dL[NCOEF];          // d^CHUNK_LEN
};

struct PairArgs {
  float c, d;
  float apw[6];             // (d^SEG)^(2^i), i=0..5 (lane powers)
  float A;                  // (d^SEG)^64 (wave power)
  int   coefIdx;            // index into Y rows*6+coef
  int   shift;              // circular shift (K4)
};

// Fill sq[SEG] with c * clip(0.5*(x0±x1)^2, EPS). If P != nullptr read the
// pre-squared array instead (half the loads).
__device__ __forceinline__ void load_sq_scaled(
    const float* __restrict__ P,
    const float* __restrict__ xpred, const float* __restrict__ xtrue,
    int row, long base, float c, float* sq)
{
  if (P != nullptr) {
    const float4* Pv = (const float4*)(P + (long)row * T_LEN + base);
#pragma unroll
    for (int i = 0; i < SEG / 4; i++) {
      float4 f = Pv[i];
      sq[4*i+0] = c * f.x; sq[4*i+1] = c * f.y;
      sq[4*i+2] = c * f.z; sq[4*i+3] = c * f.w;
    }
  } else {
    const float* xb = (row < 8 ? xpred : xtrue) + (long)((row >> 1) & 3) * (2l * T_LEN);
    const float4* x0 = (const float4*)(xb + base);
    const float4* x1 = (const float4*)(xb + T_LEN + base);
    float sgn = (row & 1) ? -1.f : 1.f;
#pragma unroll
    for (int i = 0; i < SEG / 4; i++) {
      float4 a = x0[i], b = x1[i];
      float m;
      m = a.x + sgn * b.x; sq[4*i+0] = c * fmaxf(0.5f * m * m, EPS_CLIP);
      m = a.y + sgn * b.y; sq[4*i+1] = c * fmaxf(0.5f * m * m, EPS_CLIP);
      m = a.z + sgn * b.z; sq[4*i+2] = c * fmaxf(0.5f * m * m, EPS_CLIP);
      m = a.w + sgn * b.w; sq[4*i+3] = c * fmaxf(0.5f * m * m, EPS_CLIP);
    }
  }
}

// Affine-scan carry: given thread-local EMA end value v (zero-init over SEG
// samples), per-step multiplier a = d^SEG with lane powers apw[i] = a^(2^i),
// wave power A = a^64, and chunk carry Yc (EMA value at chunk start - 1),
// return the EMA value at this thread's segment start - 1.
__device__ __forceinline__ float block_scan_carry(
    float v, const float apw[6], float A, float Yc, int tid, float* ldsWT)
{
  int lane = tid & 63, w = tid >> 6;
  float S = v;  // inclusive within-wave scan with multiplier a
#pragma unroll
  for (int i = 0; i < 6; i++) {
    float up = __shfl_up(S, 1u << i, 64);
    if (lane >= (1 << i)) S = fmaf(apw[i], up, S);
  }
  float X = __shfl_up(S, 1, 64);
  if (lane == 0) X = 0.f;
  if (lane == 63) ldsWT[w] = S;       // wave totals
  __syncthreads();
  float C = 0.f;                      // carry from earlier waves
#pragma unroll
  for (int i = 0; i < 3; i++)
    if (i < w) C = fmaf(A, C, ldsWT[i]);
  float alane = 1.f;                  // a^lane
#pragma unroll
  for (int i = 0; i < 6; i++)
    if (lane & (1 << i)) alane *= apw[i];
  float Aw = (w == 0) ? 1.f : (w == 1 ? A : (w == 2 ? A * A : A * A * A));
  // carry = X + a^lane * C + a^(tid) * Yc,  a^tid = alane * Aw
  return fmaf(alane, fmaf(Aw, Yc, C), X);
}

__global__ __launch_bounds__(NTHREADS)
void k1_stage(const float* __restrict__ xpred, const float* __restrict__ xtrue,
              float* __restrict__ P, float* __restrict__ Eloc, Coefs cf)
{
  int chunk = blockIdx.x, row = blockIdx.y, tid = threadIdx.x;
  long base = (long)chunk * CHUNK_LEN + (long)tid * SEG;
  const float* xb = (row < 8 ? xpred : xtrue) + (long)((row >> 1) & 3) * (2l * T_LEN);
  const float4* x0 = (const float4*)(xb + base);
  const float4* x1 = (const float4*)(xb + T_LEN + base);
  float sgn = (row & 1) ? -1.f : 1.f;
  float4* Pv = P ? (float4*)(P + (long)row * T_LEN + base) : nullptr;

  float y[NCOEF];
#pragma unroll
  for (int s = 0; s < NCOEF; s++) y[s] = 0.f;

#pragma unroll
  for (int i = 0; i < SEG / 4; i++) {
    float4 a = x0[i], b = x1[i];
    float4 p; float m;
    m = a.x + sgn * b.x; p.x = fmaxf(0.5f * m * m, EPS_CLIP);
    m = a.y + sgn * b.y; p.y = fmaxf(0.5f * m * m, EPS_CLIP);
    m = a.z + sgn * b.z; p.z = fmaxf(0.5f * m * m, EPS_CLIP);
    m = a.w + sgn * b.w; p.w = fmaxf(0.5f * m * m, EPS_CLIP);
#pragma unroll
    for (int s = 0; s < NCOEF; s++) {
      y[s] = fmaf(cf.d[s], y[s], cf.c[s] * p.x);
      y[s] = fmaf(cf.d[s], y[s], cf.c[s] * p.y);
      y[s] = fmaf(cf.d[s], y[s], cf.c[s] * p.z);
      y[s] = fmaf(cf.d[s], y[s], cf.c[s] * p.w);
    }
    if (Pv) Pv[i] = p;
  }

  // chunk-local end value = sum_j y_j * a^(255-j)
  int e = 255 - tid;
  float val[NCOEF];
#pragma unroll
  for (int s = 0; s < NCOEF; s++) {
    float wgt = 1.f;
#pragma unroll
    for (int b = 0; b < 8; b++)
      if (e & (1 << b)) wgt *= cf.apowK1[s][b];
    val[s] = y[s] * wgt;
  }
#pragma unroll
  for (int off = 32; off > 0; off >>= 1)
#pragma unroll
    for (int s = 0; s < NCOEF; s++) val[s] += __shfl_down(val[s], off, 64);

  __shared__ float lds[4][NCOEF];
  int lane = tid & 63, w = tid >> 6;
  if (lane == 0)
#pragma unroll
    for (int s = 0; s < NCOEF; s++) lds[w][s] = val[s];
  __syncthreads();
  if (tid == 0) {
#pragma unroll
    for (int s = 0; s < NCOEF; s++)
      Eloc[chunk * 96 + row * 6 + s] = lds[0][s] + lds[1][s] + lds[2][s] + lds[3][s];
  }
}

__global__ void k2_scan(const float* __restrict__ Eloc, float* __restrict__ Y, Coefs cf)
{
  int t = threadIdx.x;
  if (t >= 96) return;
  float dL = cf.dL[t % 6];
  float y = 0.f;
#pragma unroll 8
  for (int c = 0; c < CHUNKS; c++) {
    y = fmaf(dL, y, Eloc[c * 96 + t]);
    Y[c * 96 + t] = y;   // global EMA value at end of chunk c
  }
}

__global__ __launch_bounds__(NTHREADS)
void k3_long(const float* __restrict__ P,
             const float* __restrict__ xpred, const float* __restrict__ xtrue,
             const float* __restrict__ Y, float* __restrict__ E, PairArgs pa)
{
  int chunk = blockIdx.x, r = blockIdx.y, tid = threadIdx.x;
  long base = (long)chunk * CHUNK_LEN + (long)tid * SEG;
  float c = pa.c, d = pa.d;

  float sqp[SEG], sqt[SEG];
  load_sq_scaled(P, xpred, xtrue, r,     base, c, sqp);
  load_sq_scaled(P, xpred, xtrue, r + 8, base, c, sqt);

  float vp = 0.f, vt = 0.f;
#pragma unroll
  for (int m = 0; m < SEG; m++) { vp = fmaf(d, vp, sqp[m]); vt = fmaf(d, vt, sqt[m]); }

  float Ycp = (chunk > 0) ? Y[(chunk - 1) * 96 + r * 6 + pa.coefIdx]       : 0.f;
  float Yct = (chunk > 0) ? Y[(chunk - 1) * 96 + (r + 8) * 6 + pa.coefIdx] : 0.f;

  __shared__ float wtp[4], wtt[4];
  float cp = block_scan_carry(vp, pa.apw, pa.A, Ycp, tid, wtp);
  float ct = block_scan_carry(vt, pa.apw, pa.A, Yct, tid, wtt);

  float yp = cp, yt = ct;
  float4* Ev = (float4*)(E + (long)r * T_LEN + base);
#pragma unroll
  for (int i = 0; i < SEG / 4; i++) {
    float4 o;
    yp = fmaf(d, yp, sqp[4*i+0]); yt = fmaf(d, yt, sqt[4*i+0]); o.x = __logf(__fdividef(yp, yt));
    yp = fmaf(d, yp, sqp[4*i+1]); yt = fmaf(d, yt, sqt[4*i+1]); o.y = __logf(__fdividef(yp, yt));
    yp = fmaf(d, yp, sqp[4*i+2]); yt = fmaf(d, yt, sqt[4*i+2]); o.z = __logf(__fdividef(yp, yt));
    yp = fmaf(d, yp, sqp[4*i+3]); yt = fmaf(d, yt, sqt[4*i+3]); o.w = __logf(__fdividef(yp, yt));
    Ev[i] = o;
  }
}

__global__ __launch_bounds__(NTHREADS)
void k4_reduce(const float* __restrict__ P,
               const float* __restrict__ xpred, const float* __restrict__ xtrue,
               const float* __restrict__ Y, const float* __restrict__ E,
               float* __restrict__ part, PairArgs pa, int pair)
{
  int chunk = blockIdx.x, r = blockIdx.y, tid = threadIdx.x;
  long base = (long)chunk * CHUNK_LEN + (long)tid * SEG;
  float c = pa.c, d = pa.d;

  float sqp[SEG], sqt[SEG];
  load_sq_scaled(P, xpred, xtrue, r,     base, c, sqp);
  load_sq_scaled(P, xpred, xtrue, r + 8, base, c, sqt);

  float vp = 0.f, vt = 0.f;
#pragma unroll
  for (int m = 0; m < SEG; m++) { vp = fmaf(d, vp, sqp[m]); vt = fmaf(d, vt, sqt[m]); }

  float Ycp = (chunk > 0) ? Y[(chunk - 1) * 96 + r * 6 + pa.coefIdx]       : 0.f;
  float Yct = (chunk > 0) ? Y[(chunk - 1) * 96 + (r + 8) * 6 + pa.coefIdx] : 0.f;

  __shared__ float wtp[4], wtt[4];
  float cp = block_scan_carry(vp, pa.apw, pa.A, Ycp, tid, wtp);
  float ct = block_scan_carry(vt, pa.apw, pa.A, Yct, tid, wtt);

  const float* Er = E + (long)r * T_LEN;
  int u0 = (int)base + pa.shift;
  float yp = cp, yt = ct, accv = 0.f;
#pragma unroll
  for (int m = 0; m < SEG; m++) {
    yp = fmaf(d, yp, sqp[m]); yt = fmaf(d, yt, sqt[m]);
    float D = __logf(__fdividef(yp, yt));
    int u = u0 + m; if (u >= T_LEN) u -= T_LEN;
    accv += fabsf(D - Er[u]);
  }

#pragma unroll
  for (int off = 32; off > 0; off >>= 1) accv += __shfl_down(accv, off, 64);
  __shared__ float psum[4];
  int lane = tid & 63, w = tid >> 6;
  if (lane == 0) psum[w] = accv;
  __syncthreads();
  if (tid == 0) part[pair * 1024 + r * 128 + chunk] = psum[0] + psum[1] + psum[2] + psum[3];
}

__global__ void k5_final(const float* __restrict__ part, float* __restrict__ out)
{
  __shared__ double lds[256];
  int tid = threadIdx.x;
  double s = 0.0;
  for (int i = tid; i < 3072; i += 256) s += (double)part[i];
  lds[tid] = s; __syncthreads();
  for (int o = 128; o > 0; o >>= 1) {
    if (tid < o) lds[tid] += lds[tid + o];
    __syncthreads();
  }
  if (tid == 0) out[0] = (float)(lds[0] * (1.0 / (8.0 * 1048576.0)));
}

extern "C" void kernel_launch(void* const* d_in, const int* in_sizes, int n_in,
                              void* d_out, int out_size, void* d_ws, size_t ws_size,
                              hipStream_t stream)
{
  (void)in_sizes; (void)n_in; (void)out_size;
  const float* xpred = (const float*)d_in[0];
  const float* xtrue = (const float*)d_in[1];
  float* out = (float*)d_out;
  char* ws = (char*)d_ws;

  // workspace layout
  const size_t OFF_ELOC = 0;                       // 16*6*128 floats = 49152 B
  const size_t OFF_Y    = 49152;                   // 49152 B
  const size_t OFF_PART = 98304;                   // 3072 floats = 12288 B
  const size_t OFF_P    = 110592;                  // 64 MB
  const size_t P_BYTES  = (size_t)NROWS * T_LEN * 4;     // 67108864
  const size_t E_BYTES  = (size_t)8 * T_LEN * 4;         // 33554432
  bool useP = ws_size >= OFF_P + P_BYTES + E_BYTES;
  float* Eloc = (float*)(ws + OFF_ELOC);
  float* Ybuf = (float*)(ws + OFF_Y);
  float* part = (float*)(ws + OFF_PART);
  float* P    = useP ? (float*)(ws + OFF_P) : nullptr;
  float* E    = (float*)(ws + OFF_P + (useP ? P_BYTES : 0));

  static const double S_MS[3] = {10.0, 50.0, 100.0};
  static const double L_MS[3] = {500.0, 1500.0, 3000.0};
  static const int    SHIFT[3] = {10804, 31972, 63945};

  Coefs cf;
  for (int k = 0; k < 3; k++) {
    for (int which = 0; which < 2; which++) {
      int idx = 2 * k + which;
      double ms = which ? L_MS[k] : S_MS[k];
      double dd = std::exp(-2200.0 / (ms * 44100.0));
      float cF = (float)(1.0 - dd);   // matches jnp.asarray(coef, f32)
      float dF = 1.0f - cF;           // matches 1.0f - coef in fp32
      cf.c[idx] = cF; cf.d[idx] = dF;
      double aSEG = std::pow((double)dF, (double)SEG);
      for (int i = 0; i < 8; i++)
        cf.apowK1[idx][i] = (float)std::pow(aSEG, (double)(1 << i));
      cf.dL[idx] = (float)std::pow((double)dF, (double)CHUNK_LEN);
    }
  }
  auto mkpa = [&](int k, int which) {
    PairArgs pa;
    int idx = 2 * k + which;
    pa.c = cf.c[idx]; pa.d = cf.d[idx];
    for (int i = 0; i < 6; i++) pa.apw[i] = cf.apowK1[idx][i];
    pa.A = cf.apowK1[idx][6];  // (d^SEG)^64
    pa.coefIdx = idx;
    pa.shift = SHIFT[k];
    return pa;
  };

  k1_stage<<<dim3(CHUNKS, NROWS), NTHREADS, 0, stream>>>(xpred, xtrue, P, Eloc, cf);
  k2_scan<<<1, 128, 0, stream>>>(Eloc, Ybuf, cf);
  for (int k = 0; k < 3; k++) {
    PairArgs pl = mkpa(k, 1);
    PairArgs ps = mkpa(k, 0);
    k3_long<<<dim3(CHUNKS, 8), NTHREADS, 0, stream>>>(P, xpred, xtrue, Ybuf, E, pl);
    k4_reduce<<<dim3(CHUNKS, 8), NTHREADS, 0, stream>>>(P, xpred, xtrue, Ybuf, E, part, ps, k);
  }
  k5_final<<<1, 256, 0, stream>>>(part, out);
}

// Round 2
// 258.105 us; speedup vs baseline: 1.3692x; 1.3692x over previous
//
#include <hip/hip_runtime.h>
#include <cmath>

// MLDR loss on MI355X, v2: no P materialization.
//  K1: raw -> per-chunk local EMA end values, all 6 coefs x 16 rows.
//      Each block computes BOTH m and s rows from one channel-pair read.
//  K2: serial scan over 128 chunk carries -> global chunk-end EMA Y.
//  per pair k (3x):
//    K3: long-coef EMA reconstruction from raw (4 streams/block), writes
//        E[8][T] = log(yP/yT) (32 MB buffer, reused per pair).
//    K4: short-coef EMA reconstruction from raw + gather E at (t+shift)%T,
//        reduce |D-E| -> per-block partials.
//  K5: fp64 sum of partials / (8*T).

#define T_LEN     1048576
#define CHUNKS    128
#define CHUNK_LEN 8192
#define NT1       256
#define SEG1      32        // CHUNK_LEN / NT1
#define NT3       512
#define SEG3      16        // CHUNK_LEN / NT3
#define NCOEF     6
#define EPS_CLIP  1e-8f

struct Coefs {
  float c[NCOEF];
  float d[NCOEF];
  float apowK1[NCOEF][8];   // (d^SEG1)^(2^i), i=0..7
  float dL[NCOEF];          // d^CHUNK_LEN
};

struct PairArgs {
  float c, d;
  float apw[6];             // (d^SEG3)^(2^i), i=0..5 (lane powers)
  float A;                  // (d^SEG3)^64 = d^1024 (wave power)
  int   coefIdx;
  int   shift;
};

// ---------------- K1: locals for all coefs, both m/s rows ----------------
__global__ __launch_bounds__(NT1)
void k1_stage(const float* __restrict__ xpred, const float* __restrict__ xtrue,
              float* __restrict__ Eloc, Coefs cf)
{
  int chunk = blockIdx.x, b = blockIdx.y;          // b = which*4 + sig
  int which = b >> 2, sig = b & 3, tid = threadIdx.x;
  long base = (long)chunk * CHUNK_LEN + (long)tid * SEG1;
  const float* xb = (which ? xtrue : xpred) + (long)sig * 2 * T_LEN;
  const float4* x0 = (const float4*)(xb + base);
  const float4* x1 = (const float4*)(xb + T_LEN + base);

  float ym[NCOEF], ys[NCOEF];
#pragma unroll
  for (int s = 0; s < NCOEF; s++) { ym[s] = 0.f; ys[s] = 0.f; }

#pragma unroll
  for (int i = 0; i < SEG1 / 4; i++) {
    float4 a = x0[i], c4 = x1[i];
    float sm, sp, pm, ps;
#define STEP(CMP) \
    sm = a.CMP + c4.CMP; sp = a.CMP - c4.CMP; \
    pm = fmaxf(0.5f * sm * sm, EPS_CLIP); ps = fmaxf(0.5f * sp * sp, EPS_CLIP); \
    _Pragma("unroll") \
    for (int s = 0; s < NCOEF; s++) { \
      ym[s] = fmaf(cf.d[s], ym[s], cf.c[s] * pm); \
      ys[s] = fmaf(cf.d[s], ys[s], cf.c[s] * ps); \
    }
    STEP(x) STEP(y) STEP(z) STEP(w)
#undef STEP
  }

  // weight a^(255-tid), a = d^SEG1
  int e = (NT1 - 1) - tid;
  float vm[NCOEF], vs[NCOEF];
#pragma unroll
  for (int s = 0; s < NCOEF; s++) {
    float wgt = 1.f;
#pragma unroll
    for (int bb = 0; bb < 8; bb++)
      if (e & (1 << bb)) wgt *= cf.apowK1[s][bb];
    vm[s] = ym[s] * wgt; vs[s] = ys[s] * wgt;
  }
#pragma unroll
  for (int off = 32; off > 0; off >>= 1) {
#pragma unroll
    for (int s = 0; s < NCOEF; s++) {
      vm[s] += __shfl_down(vm[s], off, 64);
      vs[s] += __shfl_down(vs[s], off, 64);
    }
  }
  __shared__ float lds[4][2][NCOEF];
  int lane = tid & 63, w = tid >> 6;
  if (lane == 0) {
#pragma unroll
    for (int s = 0; s < NCOEF; s++) { lds[w][0][s] = vm[s]; lds[w][1][s] = vs[s]; }
  }
  __syncthreads();
  if (tid == 0) {
    int rm = which * 8 + sig * 2;
#pragma unroll
    for (int s = 0; s < NCOEF; s++) {
      Eloc[chunk * 96 + rm * 6 + s]       = lds[0][0][s] + lds[1][0][s] + lds[2][0][s] + lds[3][0][s];
      Eloc[chunk * 96 + (rm + 1) * 6 + s] = lds[0][1][s] + lds[1][1][s] + lds[2][1][s] + lds[3][1][s];
    }
  }
}

// ---------------- K2: serial chunk scan ----------------
__global__ void k2_scan(const float* __restrict__ Eloc, float* __restrict__ Y, Coefs cf)
{
  int t = threadIdx.x;
  if (t >= 96) return;
  float dL = cf.dL[t % 6];
  float y = 0.f;
#pragma unroll 8
  for (int c = 0; c < CHUNKS; c++) {
    y = fmaf(dL, y, Eloc[c * 96 + t]);
    Y[c * 96 + t] = y;
  }
}

// ---------------- batched 4-state block scan carry (8 waves) ----------------
__device__ __forceinline__ void scan4(const float v[4], const float apw[6], float A,
                                      const float Yc[4], int tid,
                                      float (*WT)[4], float cin[4])
{
  int lane = tid & 63, w = tid >> 6;
  float S[4] = { v[0], v[1], v[2], v[3] };
#pragma unroll
  for (int i = 0; i < 6; i++) {
#pragma unroll
    for (int k = 0; k < 4; k++) {
      float up = __shfl_up(S[k], 1u << i, 64);
      if (lane >= (1 << i)) S[k] = fmaf(apw[i], up, S[k]);
    }
  }
  float X[4];
#pragma unroll
  for (int k = 0; k < 4; k++) {
    X[k] = __shfl_up(S[k], 1, 64);
    if (lane == 0) X[k] = 0.f;
  }
  if (lane == 63) {
#pragma unroll
    for (int k = 0; k < 4; k++) WT[w][k] = S[k];
  }
  __syncthreads();
  float C[4] = {0.f, 0.f, 0.f, 0.f};
#pragma unroll
  for (int i = 0; i < 8; i++) {
    if (i < w) {
#pragma unroll
      for (int k = 0; k < 4; k++) C[k] = fmaf(A, C[k], WT[i][k]);
    }
  }
  float alane = 1.f;
#pragma unroll
  for (int i = 0; i < 6; i++)
    if (lane & (1 << i)) alane *= apw[i];
  float Aw = 1.f, Ap = A;
#pragma unroll
  for (int i = 0; i < 3; i++) { if (w & (1 << i)) Aw *= Ap; Ap *= Ap; }
#pragma unroll
  for (int k = 0; k < 4; k++)
    cin[k] = fmaf(alane, fmaf(Aw, Yc[k], C[k]), X[k]);
}

// load 4 sq streams (pred-m, pred-s, true-m, true-s), scaled by c
__device__ __forceinline__ void load4(const float* __restrict__ xpred,
                                      const float* __restrict__ xtrue,
                                      int sig, long base, float c,
                                      float* spm, float* sps, float* stm, float* sts)
{
  const float* pb = xpred + (long)sig * 2 * T_LEN;
  const float* tb = xtrue + (long)sig * 2 * T_LEN;
  const float4* p0 = (const float4*)(pb + base);
  const float4* p1 = (const float4*)(pb + T_LEN + base);
  const float4* t0 = (const float4*)(tb + base);
  const float4* t1 = (const float4*)(tb + T_LEN + base);
#pragma unroll
  for (int i = 0; i < SEG3 / 4; i++) {
    float4 a = p0[i], b = p1[i], u = t0[i], v = t1[i];
    float m;
#define Q(CMP, J) \
    m = a.CMP + b.CMP; spm[4*i+J] = c * fmaxf(0.5f * m * m, EPS_CLIP); \
    m = a.CMP - b.CMP; sps[4*i+J] = c * fmaxf(0.5f * m * m, EPS_CLIP); \
    m = u.CMP + v.CMP; stm[4*i+J] = c * fmaxf(0.5f * m * m, EPS_CLIP); \
    m = u.CMP - v.CMP; sts[4*i+J] = c * fmaxf(0.5f * m * m, EPS_CLIP);
    Q(x,0) Q(y,1) Q(z,2) Q(w,3)
#undef Q
  }
}

// ---------------- K3: long-coef reconstruction -> E ----------------
__global__ __launch_bounds__(NT3)
void k3_long(const float* __restrict__ xpred, const float* __restrict__ xtrue,
             const float* __restrict__ Y, float* __restrict__ E, PairArgs pa)
{
  int chunk = blockIdx.x, sig = blockIdx.y, tid = threadIdx.x;
  long base = (long)chunk * CHUNK_LEN + (long)tid * SEG3;
  float d = pa.d;

  float spm[SEG3], sps[SEG3], stm[SEG3], sts[SEG3];
  load4(xpred, xtrue, sig, base, pa.c, spm, sps, stm, sts);

  float v[4] = {0.f, 0.f, 0.f, 0.f};
#pragma unroll
  for (int m = 0; m < SEG3; m++) {
    v[0] = fmaf(d, v[0], spm[m]); v[1] = fmaf(d, v[1], sps[m]);
    v[2] = fmaf(d, v[2], stm[m]); v[3] = fmaf(d, v[3], sts[m]);
  }
  int rm = sig * 2, rs = rm + 1;
  float Yc[4] = {0.f, 0.f, 0.f, 0.f};
  if (chunk > 0) {
    const float* Yp = Y + (chunk - 1) * 96;
    Yc[0] = Yp[rm * 6 + pa.coefIdx];       Yc[1] = Yp[rs * 6 + pa.coefIdx];
    Yc[2] = Yp[(8 + rm) * 6 + pa.coefIdx]; Yc[3] = Yp[(8 + rs) * 6 + pa.coefIdx];
  }
  __shared__ float WT[8][4];
  float cin[4];
  scan4(v, pa.apw, pa.A, Yc, tid, WT, cin);

  float y0 = cin[0], y1 = cin[1], y2 = cin[2], y3 = cin[3];
  float4* Em = (float4*)(E + (long)rm * T_LEN + base);
  float4* Es = (float4*)(E + (long)rs * T_LEN + base);
#pragma unroll
  for (int i = 0; i < SEG3 / 4; i++) {
    float4 om, os;
#define R(CMP, J) \
    y0 = fmaf(d, y0, spm[4*i+J]); y1 = fmaf(d, y1, sps[4*i+J]); \
    y2 = fmaf(d, y2, stm[4*i+J]); y3 = fmaf(d, y3, sts[4*i+J]); \
    om.CMP = __logf(__fdividef(y0, y2)); os.CMP = __logf(__fdividef(y1, y3));
    R(x,0) R(y,1) R(z,2) R(w,3)
#undef R
    Em[i] = om; Es[i] = os;
  }
}

// ---------------- K4: short-coef reconstruction + gather + reduce ----------------
__global__ __launch_bounds__(NT3)
void k4_reduce(const float* __restrict__ xpred, const float* __restrict__ xtrue,
               const float* __restrict__ Y, const float* __restrict__ E,
               float* __restrict__ part, PairArgs pa, int pair)
{
  int chunk = blockIdx.x, sig = blockIdx.y, tid = threadIdx.x;
  long base = (long)chunk * CHUNK_LEN + (long)tid * SEG3;
  float d = pa.d;

  float spm[SEG3], sps[SEG3], stm[SEG3], sts[SEG3];
  load4(xpred, xtrue, sig, base, pa.c, spm, sps, stm, sts);

  float v[4] = {0.f, 0.f, 0.f, 0.f};
#pragma unroll
  for (int m = 0; m < SEG3; m++) {
    v[0] = fmaf(d, v[0], spm[m]); v[1] = fmaf(d, v[1], sps[m]);
    v[2] = fmaf(d, v[2], stm[m]); v[3] = fmaf(d, v[3], sts[m]);
  }
  int rm = sig * 2, rs = rm + 1;
  float Yc[4] = {0.f, 0.f, 0.f, 0.f};
  if (chunk > 0) {
    const float* Yp = Y + (chunk - 1) * 96;
    Yc[0] = Yp[rm * 6 + pa.coefIdx];       Yc[1] = Yp[rs * 6 + pa.coefIdx];
    Yc[2] = Yp[(8 + rm) * 6 + pa.coefIdx]; Yc[3] = Yp[(8 + rs) * 6 + pa.coefIdx];
  }
  __shared__ float WT[8][4];
  float cin[4];
  scan4(v, pa.apw, pa.A, Yc, tid, WT, cin);

  const float* Em = E + (long)rm * T_LEN;
  const float* Es = E + (long)rs * T_LEN;
  int u0 = (int)base + pa.shift;
  float y0 = cin[0], y1 = cin[1], y2 = cin[2], y3 = cin[3], acc = 0.f;
#pragma unroll
  for (int m = 0; m < SEG3; m++) {
    y0 = fmaf(d, y0, spm[m]); y1 = fmaf(d, y1, sps[m]);
    y2 = fmaf(d, y2, stm[m]); y3 = fmaf(d, y3, sts[m]);
    float Dm = __logf(__fdividef(y0, y2));
    float Ds = __logf(__fdividef(y1, y3));
    int u = u0 + m; if (u >= T_LEN) u -= T_LEN;
    acc += fabsf(Dm - Em[u]) + fabsf(Ds - Es[u]);
  }

#pragma unroll
  for (int off = 32; off > 0; off >>= 1) acc += __shfl_down(acc, off, 64);
  __shared__ float psum[8];
  int lane = tid & 63, w = tid >> 6;
  if (lane == 0) psum[w] = acc;
  __syncthreads();
  if (tid == 0) {
    float s = 0.f;
#pragma unroll
    for (int i = 0; i < 8; i++) s += psum[i];
    part[pair * 512 + sig * 128 + chunk] = s;
  }
}

__global__ void k5_final(const float* __restrict__ part, float* __restrict__ out)
{
  __shared__ double lds[256];
  int tid = threadIdx.x;
  double s = 0.0;
  for (int i = tid; i < 1536; i += 256) s += (double)part[i];
  lds[tid] = s; __syncthreads();
  for (int o = 128; o > 0; o >>= 1) {
    if (tid < o) lds[tid] += lds[tid + o];
    __syncthreads();
  }
  if (tid == 0) out[0] = (float)(lds[0] * (1.0 / (8.0 * 1048576.0)));
}

extern "C" void kernel_launch(void* const* d_in, const int* in_sizes, int n_in,
                              void* d_out, int out_size, void* d_ws, size_t ws_size,
                              hipStream_t stream)
{
  (void)in_sizes; (void)n_in; (void)out_size; (void)ws_size;
  const float* xpred = (const float*)d_in[0];
  const float* xtrue = (const float*)d_in[1];
  float* out = (float*)d_out;
  char* ws = (char*)d_ws;

  const size_t OFF_ELOC = 0;        // 128*96*4 = 49152
  const size_t OFF_Y    = 49152;    // 49152
  const size_t OFF_PART = 98304;    // 1536*4 = 6144
  const size_t OFF_E    = 110592;   // 32 MB
  float* Eloc = (float*)(ws + OFF_ELOC);
  float* Ybuf = (float*)(ws + OFF_Y);
  float* part = (float*)(ws + OFF_PART);
  float* E    = (float*)(ws + OFF_E);

  static const double S_MS[3] = {10.0, 50.0, 100.0};
  static const double L_MS[3] = {500.0, 1500.0, 3000.0};
  static const int    SHIFT[3] = {10804, 31972, 63945};

  Coefs cf;
  double a16pow[NCOEF][7];  // (d^SEG3)^(2^i), i=0..6
  for (int k = 0; k < 3; k++) {
    for (int which = 0; which < 2; which++) {
      int idx = 2 * k + which;
      double ms = which ? L_MS[k] : S_MS[k];
      double dd = std::exp(-2200.0 / (ms * 44100.0));
      float cF = (float)(1.0 - dd);
      float dF = 1.0f - cF;
      cf.c[idx] = cF; cf.d[idx] = dF;
      double aS1 = std::pow((double)dF, (double)SEG1);
      for (int i = 0; i < 8; i++)
        cf.apowK1[idx][i] = std::pow(aS1, (double)(1 << i));
      cf.dL[idx] = (float)std::pow((double)dF, (double)CHUNK_LEN);
      double aS3 = std::pow((double)dF, (double)SEG3);
      for (int i = 0; i < 7; i++)
        a16pow[idx][i] = std::pow(aS3, (double)(1 << i));
    }
  }
  auto mkpa = [&](int k, int which) {
    PairArgs pa;
    int idx = 2 * k + which;
    pa.c = cf.c[idx]; pa.d = cf.d[idx];
    for (int i = 0; i < 6; i++) pa.apw[i] = (float)a16pow[idx][i];
    pa.A = (float)a16pow[idx][6];   // (d^16)^64 = d^1024
    pa.coefIdx = idx;
    pa.shift = SHIFT[k];
    return pa;
  };

  k1_stage<<<dim3(CHUNKS, 8), NT1, 0, stream>>>(xpred, xtrue, Eloc, cf);
  k2_scan<<<1, 128, 0, stream>>>(Eloc, Ybuf, cf);
  for (int k = 0; k < 3; k++) {
    PairArgs pl = mkpa(k, 1);
    PairArgs ps = mkpa(k, 0);
    k3_long<<<dim3(CHUNKS, 4), NT3, 0, stream>>>(xpred, xtrue, Ybuf, E, pl);
    k4_reduce<<<dim3(CHUNKS, 4), NT3, 0, stream>>>(xpred, xtrue, Ybuf, E, part, ps, k);
  }
  k5_final<<<1, 256, 0, stream>>>(part, out);
}

// Round 3
// 190.430 us; speedup vs baseline: 1.8558x; 1.3554x over previous
//
#include <hip/hip_runtime.h>
#include <hip/hip_fp16.h>
#include <cmath>

// MLDR loss on MI355X, v3: pair-fused, fp16 E buffer.
//  K1: raw -> per-chunk local EMA end values, all 6 coefs x 16 rows.
//  K2: serial scan over 128 chunk carries -> global chunk-end EMA Y.
//  K3all: ALL 3 long coefs from one 4-stream raw read (12 scan states),
//         writes E[3][8][T] = log(yP/yT) as fp16 (48 MB).
//  K4all: ALL 3 short coefs + gather E at (t+shift_k)%T, reduce -> partials.
//  K5: fp64 sum / (8*T).

#define T_LEN     1048576
#define CHUNKS    128
#define CHUNK_LEN 8192
#define NT1       256
#define SEG1      32        // CHUNK_LEN / NT1
#define NT3       512
#define SEG3      16        // CHUNK_LEN / NT3
#define NCOEF     6
#define EPS_CLIP  1e-8f

struct Coefs {
  float c[NCOEF];
  float d[NCOEF];
  float apowK1[NCOEF][8];   // (d^SEG1)^(2^i)
  float dL[NCOEF];          // d^CHUNK_LEN
};

struct AllArgs {            // 3 coefs of one kind (long or short)
  float c[3], d[3];
  float apw[3][6];          // (d^SEG3)^(2^i), i=0..5
  float A[3];               // d^1024
  int   ci[3];              // coef index into Y rows
};

__device__ __constant__ const int D_SHIFT[3] = {10804, 31972, 63945};

// ---------------- K1 ----------------
__global__ __launch_bounds__(NT1)
void k1_stage(const float* __restrict__ xpred, const float* __restrict__ xtrue,
              float* __restrict__ Eloc, Coefs cf)
{
  int chunk = blockIdx.x, b = blockIdx.y;          // b = which*4 + sig
  int which = b >> 2, sig = b & 3, tid = threadIdx.x;
  long base = (long)chunk * CHUNK_LEN + (long)tid * SEG1;
  const float* xb = (which ? xtrue : xpred) + (long)sig * 2 * T_LEN;
  const float4* x0 = (const float4*)(xb + base);
  const float4* x1 = (const float4*)(xb + T_LEN + base);

  float ym[NCOEF], ys[NCOEF];
#pragma unroll
  for (int s = 0; s < NCOEF; s++) { ym[s] = 0.f; ys[s] = 0.f; }

#pragma unroll
  for (int i = 0; i < SEG1 / 4; i++) {
    float4 a = x0[i], c4 = x1[i];
    float sm, sp, pm, ps;
#define STEP(CMP) \
    sm = a.CMP + c4.CMP; sp = a.CMP - c4.CMP; \
    pm = fmaxf(0.5f * sm * sm, EPS_CLIP); ps = fmaxf(0.5f * sp * sp, EPS_CLIP); \
    _Pragma("unroll") \
    for (int s = 0; s < NCOEF; s++) { \
      ym[s] = fmaf(cf.d[s], ym[s], cf.c[s] * pm); \
      ys[s] = fmaf(cf.d[s], ys[s], cf.c[s] * ps); \
    }
    STEP(x) STEP(y) STEP(z) STEP(w)
#undef STEP
  }

  int e = (NT1 - 1) - tid;
  float vm[NCOEF], vs[NCOEF];
#pragma unroll
  for (int s = 0; s < NCOEF; s++) {
    float wgt = 1.f;
#pragma unroll
    for (int bb = 0; bb < 8; bb++)
      if (e & (1 << bb)) wgt *= cf.apowK1[s][bb];
    vm[s] = ym[s] * wgt; vs[s] = ys[s] * wgt;
  }
#pragma unroll
  for (int off = 32; off > 0; off >>= 1) {
#pragma unroll
    for (int s = 0; s < NCOEF; s++) {
      vm[s] += __shfl_down(vm[s], off, 64);
      vs[s] += __shfl_down(vs[s], off, 64);
    }
  }
  __shared__ float lds[4][2][NCOEF];
  int lane = tid & 63, w = tid >> 6;
  if (lane == 0) {
#pragma unroll
    for (int s = 0; s < NCOEF; s++) { lds[w][0][s] = vm[s]; lds[w][1][s] = vs[s]; }
  }
  __syncthreads();
  if (tid == 0) {
    int rm = which * 8 + sig * 2;
#pragma unroll
    for (int s = 0; s < NCOEF; s++) {
      Eloc[chunk * 96 + rm * 6 + s]       = lds[0][0][s] + lds[1][0][s] + lds[2][0][s] + lds[3][0][s];
      Eloc[chunk * 96 + (rm + 1) * 6 + s] = lds[0][1][s] + lds[1][1][s] + lds[2][1][s] + lds[3][1][s];
    }
  }
}

// ---------------- K2 ----------------
__global__ void k2_scan(const float* __restrict__ Eloc, float* __restrict__ Y, Coefs cf)
{
  int t = threadIdx.x;
  if (t >= 96) return;
  float dL = cf.dL[t % 6];
  float y = 0.f;
#pragma unroll 8
  for (int c = 0; c < CHUNKS; c++) {
    y = fmaf(dL, y, Eloc[c * 96 + t]);
    Y[c * 96 + t] = y;
  }
}

// ---------------- 12-state block scan ----------------
__device__ __forceinline__ void scan12(float S[12], const AllArgs& aa,
                                       const float Yc[12], int tid,
                                       float (*WT)[12], float cin[12])
{
  int lane = tid & 63, w = tid >> 6;
#pragma unroll
  for (int i = 0; i < 6; i++) {
#pragma unroll
    for (int j = 0; j < 12; j++) {
      float up = __shfl_up(S[j], 1u << i, 64);
      if (lane >= (1 << i)) S[j] = fmaf(aa.apw[j >> 2][i], up, S[j]);
    }
  }
  float X[12];
#pragma unroll
  for (int j = 0; j < 12; j++) {
    X[j] = __shfl_up(S[j], 1, 64);
    if (lane == 0) X[j] = 0.f;
  }
  if (lane == 63) {
#pragma unroll
    for (int j = 0; j < 12; j++) WT[w][j] = S[j];
  }
  __syncthreads();
  float C[12];
#pragma unroll
  for (int j = 0; j < 12; j++) C[j] = 0.f;
#pragma unroll
  for (int i = 0; i < 8; i++) {
    if (i < w) {
#pragma unroll
      for (int j = 0; j < 12; j++) C[j] = fmaf(aa.A[j >> 2], C[j], WT[i][j]);
    }
  }
  float alane[3], Aw[3];
#pragma unroll
  for (int k = 0; k < 3; k++) {
    float al = 1.f;
#pragma unroll
    for (int i = 0; i < 6; i++)
      if (lane & (1 << i)) al *= aa.apw[k][i];
    alane[k] = al;
    float aw = 1.f, ap = aa.A[k];
#pragma unroll
    for (int i = 0; i < 3; i++) { if (w & (1 << i)) aw *= ap; ap *= ap; }
    Aw[k] = aw;
  }
#pragma unroll
  for (int j = 0; j < 12; j++) {
    int k = j >> 2;
    cin[j] = fmaf(alane[k], fmaf(Aw[k], Yc[j], C[j]), X[j]);
  }
}

// unscaled squares: streams 0=pred-m 1=pred-s 2=true-m 3=true-s
__device__ __forceinline__ void load4u(const float* __restrict__ xpred,
                                       const float* __restrict__ xtrue,
                                       int sig, long base, float p[4][SEG3])
{
  const float* pb = xpred + (long)sig * 2 * T_LEN;
  const float* tb = xtrue + (long)sig * 2 * T_LEN;
  const float4* p0 = (const float4*)(pb + base);
  const float4* p1 = (const float4*)(pb + T_LEN + base);
  const float4* t0 = (const float4*)(tb + base);
  const float4* t1 = (const float4*)(tb + T_LEN + base);
#pragma unroll
  for (int i = 0; i < SEG3 / 4; i++) {
    float4 a = p0[i], b = p1[i], u = t0[i], v = t1[i];
    float m;
#define Q(CMP, J) \
    m = a.CMP + b.CMP; p[0][4*i+J] = fmaxf(0.5f * m * m, EPS_CLIP); \
    m = a.CMP - b.CMP; p[1][4*i+J] = fmaxf(0.5f * m * m, EPS_CLIP); \
    m = u.CMP + v.CMP; p[2][4*i+J] = fmaxf(0.5f * m * m, EPS_CLIP); \
    m = u.CMP - v.CMP; p[3][4*i+J] = fmaxf(0.5f * m * m, EPS_CLIP);
    Q(x,0) Q(y,1) Q(z,2) Q(w,3)
#undef Q
  }
}

__device__ __forceinline__ void localv12(const float p[4][SEG3], const AllArgs& aa, float v[12])
{
#pragma unroll
  for (int j = 0; j < 12; j++) v[j] = 0.f;
#pragma unroll
  for (int m = 0; m < SEG3; m++) {
#pragma unroll
    for (int j = 0; j < 12; j++) {
      int k = j >> 2, s = j & 3;
      v[j] = fmaf(aa.d[k], v[j], aa.c[k] * p[s][m]);
    }
  }
}

__device__ __forceinline__ void loadYc(const float* __restrict__ Y, int chunk, int sig,
                                       const AllArgs& aa, float Yc[12])
{
#pragma unroll
  for (int j = 0; j < 12; j++) Yc[j] = 0.f;
  if (chunk > 0) {
    const float* Yp = Y + (chunk - 1) * 96;
    int rm = sig * 2;
#pragma unroll
    for (int k = 0; k < 3; k++) {
      Yc[4*k+0] = Yp[rm * 6 + aa.ci[k]];
      Yc[4*k+1] = Yp[(rm + 1) * 6 + aa.ci[k]];
      Yc[4*k+2] = Yp[(8 + rm) * 6 + aa.ci[k]];
      Yc[4*k+3] = Yp[(8 + rm + 1) * 6 + aa.ci[k]];
    }
  }
}

// ---------------- K3all: 3 long coefs -> fp16 E ----------------
__global__ __launch_bounds__(NT3)
void k3all(const float* __restrict__ xpred, const float* __restrict__ xtrue,
           const float* __restrict__ Y, __half* __restrict__ E, AllArgs aa)
{
  int chunk = blockIdx.x, sig = blockIdx.y, tid = threadIdx.x;
  long base = (long)chunk * CHUNK_LEN + (long)tid * SEG3;

  float p[4][SEG3];
  load4u(xpred, xtrue, sig, base, p);

  float v[12];
  localv12(p, aa, v);
  float Yc[12];
  loadYc(Y, chunk, sig, aa, Yc);

  __shared__ float WT[8][12];
  float cin[12];
  scan12(v, aa, Yc, tid, WT, cin);

  int rm = sig * 2;
#pragma unroll
  for (int k = 0; k < 3; k++) {
    float d = aa.d[k], c = aa.c[k];
    float y0 = cin[4*k], y1 = cin[4*k+1], y2 = cin[4*k+2], y3 = cin[4*k+3];
    union { __half2 h2[8]; uint4 u4[2]; } um, us;
    float om0 = 0.f, os0 = 0.f;
#pragma unroll
    for (int m = 0; m < SEG3; m++) {
      y0 = fmaf(d, y0, c * p[0][m]); y1 = fmaf(d, y1, c * p[1][m]);
      y2 = fmaf(d, y2, c * p[2][m]); y3 = fmaf(d, y3, c * p[3][m]);
      float om = __logf(__fdividef(y0, y2));
      float os = __logf(__fdividef(y1, y3));
      if (m & 1) {
        um.h2[m >> 1] = __floats2half2_rn(om0, om);
        us.h2[m >> 1] = __floats2half2_rn(os0, os);
      } else { om0 = om; os0 = os; }
    }
    uint4* Em = (uint4*)(E + ((long)k * 8 + rm) * T_LEN + base);
    uint4* Es = (uint4*)(E + ((long)k * 8 + rm + 1) * T_LEN + base);
    Em[0] = um.u4[0]; Em[1] = um.u4[1];
    Es[0] = us.u4[0]; Es[1] = us.u4[1];
  }
}

// gather SEG3 fp16 values at (base+SH)%T from row R
__device__ __forceinline__ void gatherE(const __half* __restrict__ R, int base, int SH,
                                        bool al4, float g[SEG3])
{
  int u0 = base + SH; if (u0 >= T_LEN) u0 -= T_LEN;
  if (al4 && u0 <= T_LEN - SEG3) {
    const uint2* q = (const uint2*)(R + u0);
#pragma unroll
    for (int i = 0; i < SEG3 / 4; i++) {
      uint2 wq = q[i];
      __half2 a = *reinterpret_cast<const __half2*>(&wq.x);
      __half2 b = *reinterpret_cast<const __half2*>(&wq.y);
      g[4*i+0] = __low2float(a); g[4*i+1] = __high2float(a);
      g[4*i+2] = __low2float(b); g[4*i+3] = __high2float(b);
    }
  } else {
#pragma unroll
    for (int m = 0; m < SEG3; m++) {
      int u = u0 + m; if (u >= T_LEN) u -= T_LEN;
      g[m] = __half2float(R[u]);
    }
  }
}

// ---------------- K4all: 3 short coefs + gather + reduce ----------------
__global__ __launch_bounds__(NT3)
void k4all(const float* __restrict__ xpred, const float* __restrict__ xtrue,
           const float* __restrict__ Y, const __half* __restrict__ E,
           float* __restrict__ part, AllArgs aa)
{
  int chunk = blockIdx.x, sig = blockIdx.y, tid = threadIdx.x;
  long base = (long)chunk * CHUNK_LEN + (long)tid * SEG3;

  float p[4][SEG3];
  load4u(xpred, xtrue, sig, base, p);

  float v[12];
  localv12(p, aa, v);
  float Yc[12];
  loadYc(Y, chunk, sig, aa, Yc);

  __shared__ float WT[8][12];
  float cin[12];
  scan12(v, aa, Yc, tid, WT, cin);

  int rm = sig * 2;
  float acc = 0.f;
#pragma unroll
  for (int k = 0; k < 3; k++) {
    int SH = D_SHIFT[k];
    bool al4 = (SH % 4) == 0;   // compile-time per unrolled k
    float em[SEG3], es[SEG3];
    gatherE(E + ((long)k * 8 + rm) * T_LEN,     (int)base, SH, al4, em);
    gatherE(E + ((long)k * 8 + rm + 1) * T_LEN, (int)base, SH, al4, es);
    float d = aa.d[k], c = aa.c[k];
    float y0 = cin[4*k], y1 = cin[4*k+1], y2 = cin[4*k+2], y3 = cin[4*k+3];
#pragma unroll
    for (int m = 0; m < SEG3; m++) {
      y0 = fmaf(d, y0, c * p[0][m]); y1 = fmaf(d, y1, c * p[1][m]);
      y2 = fmaf(d, y2, c * p[2][m]); y3 = fmaf(d, y3, c * p[3][m]);
      float Dm = __logf(__fdividef(y0, y2));
      float Ds = __logf(__fdividef(y1, y3));
      acc += fabsf(Dm - em[m]) + fabsf(Ds - es[m]);
    }
  }

#pragma unroll
  for (int off = 32; off > 0; off >>= 1) acc += __shfl_down(acc, off, 64);
  __shared__ float psum[8];
  int lane = tid & 63, w = tid >> 6;
  if (lane == 0) psum[w] = acc;
  __syncthreads();
  if (tid == 0) {
    float s = 0.f;
#pragma unroll
    for (int i = 0; i < 8; i++) s += psum[i];
    part[sig * 128 + chunk] = s;
  }
}

__global__ void k5_final(const float* __restrict__ part, float* __restrict__ out)
{
  __shared__ double lds[256];
  int tid = threadIdx.x;
  double s = 0.0;
  for (int i = tid; i < 512; i += 256) s += (double)part[i];
  lds[tid] = s; __syncthreads();
  for (int o = 128; o > 0; o >>= 1) {
    if (tid < o) lds[tid] += lds[tid + o];
    __syncthreads();
  }
  if (tid == 0) out[0] = (float)(lds[0] * (1.0 / (8.0 * 1048576.0)));
}

extern "C" void kernel_launch(void* const* d_in, const int* in_sizes, int n_in,
                              void* d_out, int out_size, void* d_ws, size_t ws_size,
                              hipStream_t stream)
{
  (void)in_sizes; (void)n_in; (void)out_size; (void)ws_size;
  const float* xpred = (const float*)d_in[0];
  const float* xtrue = (const float*)d_in[1];
  float* out = (float*)d_out;
  char* ws = (char*)d_ws;

  const size_t OFF_ELOC = 0;        // 49152
  const size_t OFF_Y    = 49152;    // 49152
  const size_t OFF_PART = 98304;    // 2048
  const size_t OFF_E    = 110592;   // 3*8*T*2 = 48 MB
  float*  Eloc = (float*)(ws + OFF_ELOC);
  float*  Ybuf = (float*)(ws + OFF_Y);
  float*  part = (float*)(ws + OFF_PART);
  __half* E    = (__half*)(ws + OFF_E);

  static const double S_MS[3] = {10.0, 50.0, 100.0};
  static const double L_MS[3] = {500.0, 1500.0, 3000.0};

  Coefs cf;
  double a16pow[NCOEF][7];
  for (int k = 0; k < 3; k++) {
    for (int which = 0; which < 2; which++) {
      int idx = 2 * k + which;
      double ms = which ? L_MS[k] : S_MS[k];
      double dd = std::exp(-2200.0 / (ms * 44100.0));
      float cF = (float)(1.0 - dd);
      float dF = 1.0f - cF;
      cf.c[idx] = cF; cf.d[idx] = dF;
      double aS1 = std::pow((double)dF, (double)SEG1);
      for (int i = 0; i < 8; i++)
        cf.apowK1[idx][i] = (float)std::pow(aS1, (double)(1 << i));
      cf.dL[idx] = (float)std::pow((double)dF, (double)CHUNK_LEN);
      double aS3 = std::pow((double)dF, (double)SEG3);
      for (int i = 0; i < 7; i++)
        a16pow[idx][i] = std::pow(aS3, (double)(1 << i));
    }
  }
  auto mkall = [&](int which) {
    AllArgs aa;
    for (int k = 0; k < 3; k++) {
      int idx = 2 * k + which;
      aa.c[k] = cf.c[idx]; aa.d[k] = cf.d[idx];
      for (int i = 0; i < 6; i++) aa.apw[k][i] = (float)a16pow[idx][i];
      aa.A[k] = (float)a16pow[idx][6];
      aa.ci[k] = idx;
    }
    return aa;
  };
  AllArgs aLong = mkall(1), aShort = mkall(0);

  k1_stage<<<dim3(CHUNKS, 8), NT1, 0, stream>>>(xpred, xtrue, Eloc, cf);
  k2_scan<<<1, 128, 0, stream>>>(Eloc, Ybuf, cf);
  k3all<<<dim3(CHUNKS, 4), NT3, 0, stream>>>(xpred, xtrue, Ybuf, E, aLong);
  k4all<<<dim3(CHUNKS, 4), NT3, 0, stream>>>(xpred, xtrue, Ybuf, E, part, aShort);
  k5_final<<<1, 256, 0, stream>>>(part, out);
}